// Round 5
// baseline (60.123 us; speedup 1.0000x reference)
//
#include <hip/hip_runtime.h>

// BurstCoding: out[b,t,s] = ((t % period) < burst_length) && ((t / period) < floor(clip(x[b,s],0,1)*max_bursts))
// x: [B=16, 3, 224, 224] f32, out: [B, T=32, 3, 224, 224] f32.
//
// Rounds 1/2/4: three structures (strided-32 writes / per-plane linear /
// NT+ILP) all 53.7-55.1 us = 5.9 TB/s, vs harness fill at 6.9 TB/s.
// This round: time-separate pure-write traffic from read-mixed traffic.
//   Kernel Z: zero planes only (t%period >= bl) -> 192.7 MB pure store,
//             no reads in flight anywhere during this dispatch.
//   Kernel A: active planes, one thread per input float4, reads x ONCE,
//             computes each burst's value once, stores it bl times.
// Serialized on the same stream. If HBM read/write turnaround was the
// limiter, total -> ~48-50 us; if ~54 us again, 5.9 TB/s is the floor.
//
// Predicate simplification (exact): bidx < floor(clamp(x,0,1)*maxb)
//   <=> clamp(x,0,1)*maxb >= bidx+1   (y>=0, integer rhs)

typedef float f32x4 __attribute__((ext_vector_type(4)));

// ---- Kernel Z: inactive planes, pure streaming zero-fill ----
__global__ __launch_bounds__(256) void burst_zero_kernel(
    float* __restrict__ out,
    const int* __restrict__ p_bl, const int* __restrict__ p_ibi,
    int T, int S4)
{
    const int bl     = *p_bl;
    const int period = bl + *p_ibi;
    const int maxb   = T / period;

    const int bt   = blockIdx.y;          // b*T + t
    const int t    = bt % T;
    const int tm   = t % period;
    const int bidx = t / period;
    if (tm < bl && bidx < maxb) return;   // active plane -> kernel A

    const int s4a = blockIdx.x * (blockDim.x * 2) + threadIdx.x;
    const int s4b = s4a + blockDim.x;

    f32x4* op = reinterpret_cast<f32x4*>(out) + (long)bt * S4;
    const f32x4 z = {0.f, 0.f, 0.f, 0.f};
    if (s4a < S4) op[s4a] = z;
    if (s4b < S4) op[s4b] = z;
}

// ---- Kernel A: active planes; read x once, store each burst value bl times ----
__global__ __launch_bounds__(256) void burst_active_kernel(
    const float* __restrict__ x, float* __restrict__ out,
    const int* __restrict__ p_bl, const int* __restrict__ p_ibi,
    int T, int S4)
{
    const int bl     = *p_bl;
    const int period = bl + *p_ibi;
    const int maxb   = T / period;
    const float mbf  = (float)maxb;

    const int b  = blockIdx.y;
    const int s4 = blockIdx.x * blockDim.x + threadIdx.x;
    if (s4 >= S4) return;

    const f32x4 xv = reinterpret_cast<const f32x4*>(x)[(long)b * S4 + s4];
    const float n0 = fminf(fmaxf(xv.x, 0.f), 1.f) * mbf;
    const float n1 = fminf(fmaxf(xv.y, 0.f), 1.f) * mbf;
    const float n2 = fminf(fmaxf(xv.z, 0.f), 1.f) * mbf;
    const float n3 = fminf(fmaxf(xv.w, 0.f), 1.f) * mbf;

    f32x4* outp = reinterpret_cast<f32x4*>(out) + (long)b * T * S4 + s4;

    for (int k = 0; k < maxb; ++k) {      // one value per burst
        const float thr = (float)(k + 1);
        f32x4 v;
        v.x = (n0 >= thr) ? 1.f : 0.f;
        v.y = (n1 >= thr) ? 1.f : 0.f;
        v.z = (n2 >= thr) ? 1.f : 0.f;
        v.w = (n3 >= thr) ? 1.f : 0.f;
        const long base = (long)(k * period) * S4;
        for (int j = 0; j < bl; ++j)      // store it bl times
            outp[base + (long)j * S4] = v;
    }
}

extern "C" void kernel_launch(void* const* d_in, const int* in_sizes, int n_in,
                              void* d_out, int out_size, void* d_ws, size_t ws_size,
                              hipStream_t stream) {
    const float* x   = (const float*)d_in[0];
    // d_in[1] = timesteps (derived on host from sizes instead)
    const int* p_bl  = (const int*)d_in[2];  // burst_length
    const int* p_ibi = (const int*)d_in[3];  // interburst_interval
    float* out = (float*)d_out;

    const long N  = (long)in_sizes[0];          // B * S
    const int  T  = (int)((long)out_size / N);  // = 32
    const int  S  = 3 * 224 * 224;              // spatial elems per batch (reference setup)
    const int  S4 = S / 4;                      // 37632 float4 per plane
    const int  B  = (int)(N / S);               // 16

    const int threads = 256;

    // Z: pure-write phase over all planes (idle blocks early-out; active/zero
    //    classification needs device scalars, unknown on host)
    dim3 gz((S4 + threads * 2 - 1) / (threads * 2),  // 74
            (unsigned)(B * T));                      // 512
    burst_zero_kernel<<<gz, dim3(threads), 0, stream>>>(out, p_bl, p_ibi, T, S4);

    // A: read-once + active-plane stores
    dim3 ga((S4 + threads - 1) / threads,            // 147
            (unsigned)B);                            // 16
    burst_active_kernel<<<ga, dim3(threads), 0, stream>>>(x, out, p_bl, p_ibi, T, S4);
}

// Round 6
// 53.989 us; speedup vs baseline: 1.1136x; 1.1136x over previous
//
#include <hip/hip_runtime.h>

// BurstCoding: out[b,t,s] = ((t % period) < burst_length) && ((t / period) < floor(clip(x[b,s],0,1)*max_bursts))
// x: [B=16, 3, 224, 224] f32, out: [B, T=32, 3, 224, 224] f32.
//
// FINAL (revert to round-1 structure — best measured: 53.7 us = 5.92 TB/s,
// 94% of the 6.3 TB/s measured float4-copy ceiling on MI355X).
// Ablation history, all falsified as levers:
//   R2 per-plane linear writes        53.8 us  (access pattern: null)
//   R4 nontemporal stores + 2x ILP    55.1 us  (L2 write-allocate: null)
//   R5 pure-write/read phase split    60.1 us  (rd/wr turnaround: regression)
// Memory-bound: 308 MB write (irreducible) + 9.6 MB read. One thread per
// input float4: reads x exactly once, writes T=32 float4 planes; within a
// wave consecutive lanes write consecutive addresses in each plane ->
// fully coalesced global_store_dwordx4.

__global__ __launch_bounds__(256) void burst_coding_kernel(
    const float* __restrict__ x, float* __restrict__ out,
    const int* __restrict__ p_bl, const int* __restrict__ p_ibi,
    int T, int S4, long total4)
{
    const int bl     = *p_bl;               // burst_length (broadcast scalar load)
    const int period = bl + *p_ibi;         // burst_length + interburst_interval
    const int maxb   = T / period;
    const float mbf  = (float)maxb;

    for (long i = blockIdx.x * (long)blockDim.x + threadIdx.x; i < total4;
         i += (long)gridDim.x * blockDim.x) {
        const long b  = i / S4;             // batch index
        const int  s4 = (int)(i - b * S4);  // float4 index within spatial plane

        const float4 xv = reinterpret_cast<const float4*>(x)[i];

        // n_bursts = floor(clip(x,0,1) * max_bursts); trunc == floor for nonneg
        const int n0 = (int)(fminf(fmaxf(xv.x, 0.f), 1.f) * mbf);
        const int n1 = (int)(fminf(fmaxf(xv.y, 0.f), 1.f) * mbf);
        const int n2 = (int)(fminf(fmaxf(xv.z, 0.f), 1.f) * mbf);
        const int n3 = (int)(fminf(fmaxf(xv.w, 0.f), 1.f) * mbf);

        float4* outp = reinterpret_cast<float4*>(out) + b * (long)T * S4 + s4;

        int tmod = 0, bidx = 0;
        for (int t = 0; t < T; ++t) {
            const bool w = (tmod < bl);
            float4 v;
            v.x = (w && (bidx < n0)) ? 1.f : 0.f;
            v.y = (w && (bidx < n1)) ? 1.f : 0.f;
            v.z = (w && (bidx < n2)) ? 1.f : 0.f;
            v.w = (w && (bidx < n3)) ? 1.f : 0.f;
            outp[(long)t * S4] = v;
            if (++tmod == period) { tmod = 0; ++bidx; }
        }
    }
}

extern "C" void kernel_launch(void* const* d_in, const int* in_sizes, int n_in,
                              void* d_out, int out_size, void* d_ws, size_t ws_size,
                              hipStream_t stream) {
    const float* x   = (const float*)d_in[0];
    // d_in[1] = timesteps (derived on host from sizes instead)
    const int* p_bl  = (const int*)d_in[2];  // burst_length
    const int* p_ibi = (const int*)d_in[3];  // interburst_interval
    float* out = (float*)d_out;

    const long N  = (long)in_sizes[0];       // B * S = 16 * 150528
    const int  T  = (int)((long)out_size / N);  // = 32
    const int  S  = 3 * 224 * 224;           // spatial elems per batch (from reference setup)
    const int  S4 = S / 4;
    const long total4 = N / 4;

    const int threads = 256;
    const long blocks = (total4 + threads - 1) / threads;

    burst_coding_kernel<<<dim3((unsigned)blocks), dim3(threads), 0, stream>>>(
        x, out, p_bl, p_ibi, T, S4, total4);
}